// Round 8
// baseline (75.420 us; speedup 1.0000x reference)
//
#include <hip/hip_runtime.h>
#include <hip/hip_fp16.h>

#define CIN 32
#define COUT 64
#define NB 4
#define NPTS 32768
#define KNN 16

typedef unsigned short u16;
typedef unsigned char u8;
typedef float f2v __attribute__((ext_vector_type(2)));
typedef float f4v __attribute__((ext_vector_type(4)));
typedef int i4v __attribute__((ext_vector_type(4)));
typedef unsigned int u4v __attribute__((ext_vector_type(4)));
typedef unsigned int u2v __attribute__((ext_vector_type(2)));

__device__ __forceinline__ u16 f2h(float f) {
  _Float16 h = (_Float16)f;
  u16 u; __builtin_memcpy(&u, &h, 2); return u;
}
__device__ __forceinline__ f2v h2_to_f2(unsigned int u) {
  _Float16 a, b;
  __builtin_memcpy(&a, (const char*)&u, 2);
  __builtin_memcpy(&b, ((const char*)&u) + 2, 2);
  return (f2v){(float)a, (float)b};
}

// Kernel 1: pure GEMM + store. local (fp16) and edge (fp8 e4m3) tables,
// both (B,N,64) row-major. v_pk_fma_f32 over CIN pairs, weights s_load'd
// (wave-uniform rows). No BN, no central write (moved to k2).
__global__ __launch_bounds__(256) void k1_gemm(
    const float* __restrict__ feat, const float* __restrict__ W1,
    const float* __restrict__ W2, u16* __restrict__ lt, u8* __restrict__ et) {
  const int bid = blockIdx.x;
  const int b = bid >> 9;
  const int n0 = (bid & 511) << 6;
  const int t = threadIdx.x;
  const int lane = t & 63;
  const int wchunk = __builtin_amdgcn_readfirstlane(t >> 6);
  const int n = n0 + lane;

  f2v fv[16];
  const float* fp = feat + (size_t)b * CIN * NPTS + n;
#pragma unroll
  for (int c2 = 0; c2 < 16; ++c2)
    fv[c2] = (f2v){__builtin_nontemporal_load(fp + (size_t)(2 * c2) * NPTS),
                   __builtin_nontemporal_load(fp + (size_t)(2 * c2 + 1) * NPTS)};

  const int half = wchunk >> 1;        // 0 -> W1 (local fp16), 1 -> W2 (edge fp8)
  const int rbase = (wchunk & 1) * 32;
  const float* Wp = half ? W2 : W1;

  unsigned int pkh[16];
  unsigned int pk8[8];

#pragma unroll
  for (int oo = 0; oo < 32; oo += 4) {
    const float* w0 = Wp + (size_t)(rbase + oo) * CIN;
    const f2v* wr0 = reinterpret_cast<const f2v*>(w0);
    const f2v* wr1 = reinterpret_cast<const f2v*>(w0 + CIN);
    const f2v* wr2 = reinterpret_cast<const f2v*>(w0 + 2 * CIN);
    const f2v* wr3 = reinterpret_cast<const f2v*>(w0 + 3 * CIN);
    f2v p0 = (f2v)0.f, p1 = (f2v)0.f, p2 = (f2v)0.f, p3 = (f2v)0.f;
#pragma unroll
    for (int c2 = 0; c2 < 16; ++c2) {
      const f2v fc = fv[c2];
      p0 = __builtin_elementwise_fma(wr0[c2], fc, p0);
      p1 = __builtin_elementwise_fma(wr1[c2], fc, p1);
      p2 = __builtin_elementwise_fma(wr2[c2], fc, p2);
      p3 = __builtin_elementwise_fma(wr3[c2], fc, p3);
    }
    const float a0 = p0.x + p0.y, a1 = p1.x + p1.y;
    const float a2 = p2.x + p2.y, a3 = p3.x + p3.y;
    if (half == 0) {
      pkh[oo / 2]     = (unsigned)f2h(a0) | ((unsigned)f2h(a1) << 16);
      pkh[oo / 2 + 1] = (unsigned)f2h(a2) | ((unsigned)f2h(a3) << 16);
    } else {
      int u = 0;
      u = __builtin_amdgcn_cvt_pk_fp8_f32(a0, a1, u, false);
      u = __builtin_amdgcn_cvt_pk_fp8_f32(a2, a3, u, true);
      pk8[oo / 4] = (unsigned)u;
    }
  }
  if (half == 0) {
    u4v* dp = reinterpret_cast<u4v*>(lt + ((size_t)(b * NPTS + n)) * COUT + rbase);
#pragma unroll
    for (int q = 0; q < 4; ++q) {
      const u4v v = {pkh[4 * q], pkh[4 * q + 1], pkh[4 * q + 2], pkh[4 * q + 3]};
      __builtin_nontemporal_store(v, dp + q);
    }
  } else {
    // edge table: normal (cached) store — k2 gathers it
    u4v* dp = reinterpret_cast<u4v*>(et + ((size_t)(b * NPTS + n)) * COUT + rbase);
    dp[0] = (u4v){pk8[0], pk8[1], pk8[2], pk8[3]};
    dp[1] = (u4v){pk8[4], pk8[5], pk8[6], pk8[7]};
  }
}

// Kernel 2: full output. lane = nn*8+cg: thread owns (n = n_blk+w*8+nn,
// channels 8cg..8cg+7). Issues all 16 fp8 gathers (8B uint2; 8 cg lanes
// cover one 64B row), then computes central half (from fp16 local row,
// hides under gather latency), then diff half. All K in-lane, no shuffles.
// NT loads/stores for touch-once streams keep L2 free for the edge table.
// XCD-swizzled grid pins each batch's 2 MiB table to 2 XCDs.
__global__ __launch_bounds__(256) void k2_gather(
    const u16* __restrict__ lt, const u8* __restrict__ et,
    const int* __restrict__ knn, const float* __restrict__ gamma,
    const float* __restrict__ beta, const float* __restrict__ mean,
    const float* __restrict__ var, float* __restrict__ out) {
  __shared__ float obuf[128 * 33];
  int bid = blockIdx.x;
  bid = (bid & 7) * 512 + (bid >> 3);   // 4096 % 8 == 0 -> bijective
  const int b = bid >> 10;
  const int n_blk = (bid & 1023) << 5;  // 32 n per block
  const int t = threadIdx.x;
  const int w = t >> 6;
  const int lane = t & 63;
  const int nn = lane >> 3;   // 0..7
  const int cg = lane & 7;    // 0..7
  const int ch = cg * 8;

  const int n = n_blk + w * 8 + nn;
  const int col = w * 8 + nn;
  const size_t rowbase = (size_t)b * NPTS;

  // knn row (needed before gathers) + local row
  const i4v* kp = reinterpret_cast<const i4v*>(knn + (rowbase + n) * KNN);
  const i4v kv0 = __builtin_nontemporal_load(kp);
  const i4v kv1 = __builtin_nontemporal_load(kp + 1);
  const i4v kv2 = __builtin_nontemporal_load(kp + 2);
  const i4v kv3 = __builtin_nontemporal_load(kp + 3);
  const u4v lv = __builtin_nontemporal_load(
      reinterpret_cast<const u4v*>(lt + (rowbase + n) * COUT + ch));

  // issue all 16 gathers (8B fp8 each)
  const u8* etb = et + rowbase * COUT + ch;
  const int idx[16] = {kv0.x, kv0.y, kv0.z, kv0.w, kv1.x, kv1.y, kv1.z, kv1.w,
                       kv2.x, kv2.y, kv2.z, kv2.w, kv3.x, kv3.y, kv3.z, kv3.w};
  u2v e[16];
#pragma unroll
  for (int k = 0; k < 16; ++k)
    e[k] = *reinterpret_cast<const u2v*>(etb + ((size_t)idx[k] << 6));

  // BN constants + central half (VALU under gather latency)
  const unsigned int lw[4] = {lv.x, lv.y, lv.z, lv.w};
  f2v inv2[4], tt[4];
#pragma unroll
  for (int i = 0; i < 4; ++i) {
    const f2v l = h2_to_f2(lw[i]);
    {  // central: rows ch..ch+7
      const int r0 = ch + 2 * i;
      const float iv0 = gamma[r0] * rsqrtf(var[r0] + 1e-5f);
      const float iv1 = gamma[r0 + 1] * rsqrtf(var[r0 + 1] + 1e-5f);
      const f2v iv = (f2v){iv0, iv1};
      const f2v sh = (f2v){beta[r0] - mean[r0] * iv0,
                           beta[r0 + 1] - mean[r0 + 1] * iv1};
      const f2v cen = __builtin_elementwise_max(
          __builtin_elementwise_fma(l, iv, sh), (f2v)0.f);
      obuf[(ch + 2 * i) * 33 + col] = cen.x;
      obuf[(ch + 2 * i + 1) * 33 + col] = cen.y;
    }
    {  // diff constants: rows 64+ch..64+ch+7
      const int r0 = 64 + ch + 2 * i;
      const float iv0 = gamma[r0] * rsqrtf(var[r0] + 1e-5f);
      const float iv1 = gamma[r0 + 1] * rsqrtf(var[r0 + 1] + 1e-5f);
      inv2[i] = (f2v){iv0, iv1};
      const f2v sh = (f2v){beta[r0] - mean[r0] * iv0,
                           beta[r0 + 1] - mean[r0 + 1] * iv1};
      tt[i] = sh - l * inv2[i];
    }
  }

  f2v acc[4] = {(f2v)0.f, (f2v)0.f, (f2v)0.f, (f2v)0.f};
  const f2v zero = (f2v)0.f;
#pragma unroll
  for (int k = 0; k < 16; ++k) {
    const f2v d0 = __builtin_amdgcn_cvt_pk_f32_fp8(e[k].x, false);
    const f2v d1 = __builtin_amdgcn_cvt_pk_f32_fp8(e[k].x, true);
    const f2v d2 = __builtin_amdgcn_cvt_pk_f32_fp8(e[k].y, false);
    const f2v d3 = __builtin_amdgcn_cvt_pk_f32_fp8(e[k].y, true);
    acc[0] += __builtin_elementwise_max(__builtin_elementwise_fma(d0, inv2[0], tt[0]), zero);
    acc[1] += __builtin_elementwise_max(__builtin_elementwise_fma(d1, inv2[1], tt[1]), zero);
    acc[2] += __builtin_elementwise_max(__builtin_elementwise_fma(d2, inv2[2], tt[2]), zero);
    acc[3] += __builtin_elementwise_max(__builtin_elementwise_fma(d3, inv2[3], tt[3]), zero);
  }
#pragma unroll
  for (int i = 0; i < 4; ++i) {
    obuf[(64 + ch + 2 * i) * 33 + col] = acc[i].x * 0.0625f;
    obuf[(64 + ch + 2 * i + 1) * 33 + col] = acc[i].y * 0.0625f;
  }
  __syncthreads();
  // write 128 ch x 32 n, coalesced float4, NT (touch-once)
#pragma unroll
  for (int r = 0; r < 4; ++r) {
    const int c = r * 32 + (t >> 3);
    const int nn4 = (t & 7) * 4;
    const f4v v = {obuf[c * 33 + nn4], obuf[c * 33 + nn4 + 1],
                   obuf[c * 33 + nn4 + 2], obuf[c * 33 + nn4 + 3]};
    __builtin_nontemporal_store(
        v, reinterpret_cast<f4v*>(out + ((size_t)b * 128 + c) * NPTS + n_blk + nn4));
  }
}

extern "C" void kernel_launch(void* const* d_in, const int* in_sizes, int n_in,
                              void* d_out, int out_size, void* d_ws, size_t ws_size,
                              hipStream_t stream) {
  const float* feat  = (const float*)d_in[0];
  const int*   knn   = (const int*)d_in[1];
  const float* W1    = (const float*)d_in[2];
  const float* W2    = (const float*)d_in[3];
  const float* gamma = (const float*)d_in[4];
  const float* beta  = (const float*)d_in[5];
  const float* mean  = (const float*)d_in[6];
  const float* var   = (const float*)d_in[7];
  float* out = (float*)d_out;

  u16* lt = (u16*)d_ws;                           // (B,N,64) fp16 local, 16.8 MB
  u8* et = (u8*)(lt + (size_t)NB * NPTS * COUT);  // (B,N,64) fp8 edge, 8.4 MB

  k1_gemm<<<dim3(NB * NPTS / 64), 256, 0, stream>>>(feat, W1, W2, lt, et);
  k2_gather<<<dim3(NB * NPTS / 32), 256, 0, stream>>>(lt, et, knn, gamma, beta,
                                                      mean, var, out);
}

// Round 9
// 63.891 us; speedup vs baseline: 1.1805x; 1.1805x over previous
//
#include <hip/hip_runtime.h>
#include <hip/hip_fp16.h>

#define CIN 32
#define COUT 64
#define NB 4
#define NPTS 32768
#define KNN 16

typedef unsigned short u16;
typedef unsigned char u8;
typedef float f2v __attribute__((ext_vector_type(2)));
typedef float f4v __attribute__((ext_vector_type(4)));
typedef int i4v __attribute__((ext_vector_type(4)));
typedef unsigned int u4v __attribute__((ext_vector_type(4)));
typedef unsigned int u2v __attribute__((ext_vector_type(2)));

__device__ __forceinline__ u16 f2h(float f) {
  _Float16 h = (_Float16)f;
  u16 u; __builtin_memcpy(&u, &h, 2); return u;
}
__device__ __forceinline__ f2v h2_to_f2(unsigned int u) {
  _Float16 a, b;
  __builtin_memcpy(&a, (const char*)&u, 2);
  __builtin_memcpy(&b, ((const char*)&u) + 2, 2);
  return (f2v){(float)a, (float)b};
}

// Kernel 1: pure GEMM + store (central/BN moved to k2). All loads/stores
// CACHED: feat tiles are reused by all 4 waves of a block (L1/L2), and
// lt/et stores are wave-strided 16B — they need L2 line-merging (NT store
// here was the R8 regression). lt fp16, et fp8 e4m3, both (B,N,64).
__global__ __launch_bounds__(256) void k1_gemm(
    const float* __restrict__ feat, const float* __restrict__ W1,
    const float* __restrict__ W2, u16* __restrict__ lt, u8* __restrict__ et) {
  const int bid = blockIdx.x;
  const int b = bid >> 9;
  const int n0 = (bid & 511) << 6;
  const int t = threadIdx.x;
  const int lane = t & 63;
  const int wchunk = __builtin_amdgcn_readfirstlane(t >> 6);
  const int n = n0 + lane;

  f2v fv[16];
  const float* fp = feat + (size_t)b * CIN * NPTS + n;
#pragma unroll
  for (int c2 = 0; c2 < 16; ++c2)
    fv[c2] = (f2v){fp[(size_t)(2 * c2) * NPTS], fp[(size_t)(2 * c2 + 1) * NPTS]};

  const int half = wchunk >> 1;        // 0 -> W1 (local fp16), 1 -> W2 (edge fp8)
  const int rbase = (wchunk & 1) * 32;
  const float* Wp = half ? W2 : W1;

  unsigned int pkh[16];
  unsigned int pk8[8];

#pragma unroll
  for (int oo = 0; oo < 32; oo += 4) {
    const float* w0 = Wp + (size_t)(rbase + oo) * CIN;
    const f2v* wr0 = reinterpret_cast<const f2v*>(w0);
    const f2v* wr1 = reinterpret_cast<const f2v*>(w0 + CIN);
    const f2v* wr2 = reinterpret_cast<const f2v*>(w0 + 2 * CIN);
    const f2v* wr3 = reinterpret_cast<const f2v*>(w0 + 3 * CIN);
    f2v p0 = (f2v)0.f, p1 = (f2v)0.f, p2 = (f2v)0.f, p3 = (f2v)0.f;
#pragma unroll
    for (int c2 = 0; c2 < 16; ++c2) {
      const f2v fc = fv[c2];
      p0 = __builtin_elementwise_fma(wr0[c2], fc, p0);
      p1 = __builtin_elementwise_fma(wr1[c2], fc, p1);
      p2 = __builtin_elementwise_fma(wr2[c2], fc, p2);
      p3 = __builtin_elementwise_fma(wr3[c2], fc, p3);
    }
    const float a0 = p0.x + p0.y, a1 = p1.x + p1.y;
    const float a2 = p2.x + p2.y, a3 = p3.x + p3.y;
    if (half == 0) {
      pkh[oo / 2]     = (unsigned)f2h(a0) | ((unsigned)f2h(a1) << 16);
      pkh[oo / 2 + 1] = (unsigned)f2h(a2) | ((unsigned)f2h(a3) << 16);
    } else {
      int u = 0;
      u = __builtin_amdgcn_cvt_pk_fp8_f32(a0, a1, u, false);
      u = __builtin_amdgcn_cvt_pk_fp8_f32(a2, a3, u, true);
      pk8[oo / 4] = (unsigned)u;
    }
  }
  if (half == 0) {
    u4v* dp = reinterpret_cast<u4v*>(lt + ((size_t)(b * NPTS + n)) * COUT + rbase);
#pragma unroll
    for (int q = 0; q < 4; ++q)
      dp[q] = (u4v){pkh[4 * q], pkh[4 * q + 1], pkh[4 * q + 2], pkh[4 * q + 3]};
  } else {
    u4v* dp = reinterpret_cast<u4v*>(et + ((size_t)(b * NPTS + n)) * COUT + rbase);
    dp[0] = (u4v){pk8[0], pk8[1], pk8[2], pk8[3]};
    dp[1] = (u4v){pk8[4], pk8[5], pk8[6], pk8[7]};
  }
}

// Kernel 2: full output, 2 n's per thread for 32 in-flight gathers (2x MLP
// vs R8). lane = nn*8+cg: thread owns n in {nA, nA+32}, channels 8cg..8cg+7.
// Gathers are CACHED (et must live in L2); knn/lt loads and out stores are
// NT (touch-once; NT loads still hit L2, NT out stores are wave-contiguous).
// XCD-swizzled grid. Output staged in LDS (128ch x 64n, pad 65).
__global__ __launch_bounds__(256, 3) void k2_gather(
    const u16* __restrict__ lt, const u8* __restrict__ et,
    const int* __restrict__ knn, const float* __restrict__ gamma,
    const float* __restrict__ beta, const float* __restrict__ mean,
    const float* __restrict__ var, float* __restrict__ out) {
  __shared__ float obuf[128 * 65];
  int bid = blockIdx.x;
  bid = (bid & 7) * 256 + (bid >> 3);   // 2048 % 8 == 0 -> bijective
  const int b = bid >> 9;               // 512 blocks per batch
  const int n_blk = (bid & 511) << 6;   // 64 n per block
  const int t = threadIdx.x;
  const int w = t >> 6;
  const int lane = t & 63;
  const int nn = lane >> 3;   // 0..7
  const int cg = lane & 7;    // 0..7
  const int ch = cg * 8;

  const int colA = w * 8 + nn;          // 0..31
  const int colB = colA + 32;
  const int nA = n_blk + colA;
  const int nB = n_blk + colB;
  const size_t rowbase = (size_t)b * NPTS;

  // knn + local rows for both n (NT loads)
  const i4v* kpA = reinterpret_cast<const i4v*>(knn + (rowbase + nA) * KNN);
  const i4v* kpB = reinterpret_cast<const i4v*>(knn + (rowbase + nB) * KNN);
  i4v kA0 = __builtin_nontemporal_load(kpA);
  i4v kA1 = __builtin_nontemporal_load(kpA + 1);
  i4v kA2 = __builtin_nontemporal_load(kpA + 2);
  i4v kA3 = __builtin_nontemporal_load(kpA + 3);
  i4v kB0 = __builtin_nontemporal_load(kpB);
  i4v kB1 = __builtin_nontemporal_load(kpB + 1);
  i4v kB2 = __builtin_nontemporal_load(kpB + 2);
  i4v kB3 = __builtin_nontemporal_load(kpB + 3);
  const u4v lvA = __builtin_nontemporal_load(
      reinterpret_cast<const u4v*>(lt + (rowbase + nA) * COUT + ch));
  const u4v lvB = __builtin_nontemporal_load(
      reinterpret_cast<const u4v*>(lt + (rowbase + nB) * COUT + ch));

  // issue all 32 gathers (8B fp8 each; 8 cg lanes cover one 64B row)
  const u8* etb = et + rowbase * COUT + ch;
  const int idxA[16] = {kA0.x, kA0.y, kA0.z, kA0.w, kA1.x, kA1.y, kA1.z, kA1.w,
                        kA2.x, kA2.y, kA2.z, kA2.w, kA3.x, kA3.y, kA3.z, kA3.w};
  const int idxB[16] = {kB0.x, kB0.y, kB0.z, kB0.w, kB1.x, kB1.y, kB1.z, kB1.w,
                        kB2.x, kB2.y, kB2.z, kB2.w, kB3.x, kB3.y, kB3.z, kB3.w};
  u2v eA[16], eB[16];
#pragma unroll
  for (int k = 0; k < 16; ++k)
    eA[k] = *reinterpret_cast<const u2v*>(etb + ((size_t)(unsigned)idxA[k] << 6));
#pragma unroll
  for (int k = 0; k < 16; ++k)
    eB[k] = *reinterpret_cast<const u2v*>(etb + ((size_t)(unsigned)idxB[k] << 6));

  // BN constants + central halves (VALU hides under gather latency)
  const unsigned int lwA[4] = {lvA.x, lvA.y, lvA.z, lvA.w};
  const unsigned int lwB[4] = {lvB.x, lvB.y, lvB.z, lvB.w};
  f2v inv2[4], ttA[4], ttB[4];
#pragma unroll
  for (int i = 0; i < 4; ++i) {
    const f2v lA = h2_to_f2(lwA[i]);
    const f2v lB = h2_to_f2(lwB[i]);
    {  // central rows ch..ch+7
      const int r0 = ch + 2 * i;
      const float iv0 = gamma[r0] * rsqrtf(var[r0] + 1e-5f);
      const float iv1 = gamma[r0 + 1] * rsqrtf(var[r0 + 1] + 1e-5f);
      const f2v iv = (f2v){iv0, iv1};
      const f2v sh = (f2v){beta[r0] - mean[r0] * iv0,
                           beta[r0 + 1] - mean[r0 + 1] * iv1};
      const f2v cA = __builtin_elementwise_max(
          __builtin_elementwise_fma(lA, iv, sh), (f2v)0.f);
      const f2v cB = __builtin_elementwise_max(
          __builtin_elementwise_fma(lB, iv, sh), (f2v)0.f);
      obuf[(r0) * 65 + colA] = cA.x;
      obuf[(r0 + 1) * 65 + colA] = cA.y;
      obuf[(r0) * 65 + colB] = cB.x;
      obuf[(r0 + 1) * 65 + colB] = cB.y;
    }
    {  // diff rows 64+ch..64+ch+7
      const int r0 = 64 + ch + 2 * i;
      const float iv0 = gamma[r0] * rsqrtf(var[r0] + 1e-5f);
      const float iv1 = gamma[r0 + 1] * rsqrtf(var[r0 + 1] + 1e-5f);
      inv2[i] = (f2v){iv0, iv1};
      const f2v sh = (f2v){beta[r0] - mean[r0] * iv0,
                           beta[r0 + 1] - mean[r0 + 1] * iv1};
      ttA[i] = sh - lA * inv2[i];
      ttB[i] = sh - lB * inv2[i];
    }
  }

  const f2v zero = (f2v)0.f;
  f2v accA[4] = {zero, zero, zero, zero};
  f2v accB[4] = {zero, zero, zero, zero};
#pragma unroll
  for (int k = 0; k < 16; ++k) {
    const f2v d0 = __builtin_amdgcn_cvt_pk_f32_fp8(eA[k].x, false);
    const f2v d1 = __builtin_amdgcn_cvt_pk_f32_fp8(eA[k].x, true);
    const f2v d2 = __builtin_amdgcn_cvt_pk_f32_fp8(eA[k].y, false);
    const f2v d3 = __builtin_amdgcn_cvt_pk_f32_fp8(eA[k].y, true);
    accA[0] += __builtin_elementwise_max(__builtin_elementwise_fma(d0, inv2[0], ttA[0]), zero);
    accA[1] += __builtin_elementwise_max(__builtin_elementwise_fma(d1, inv2[1], ttA[1]), zero);
    accA[2] += __builtin_elementwise_max(__builtin_elementwise_fma(d2, inv2[2], ttA[2]), zero);
    accA[3] += __builtin_elementwise_max(__builtin_elementwise_fma(d3, inv2[3], ttA[3]), zero);
  }
#pragma unroll
  for (int k = 0; k < 16; ++k) {
    const f2v d0 = __builtin_amdgcn_cvt_pk_f32_fp8(eB[k].x, false);
    const f2v d1 = __builtin_amdgcn_cvt_pk_f32_fp8(eB[k].x, true);
    const f2v d2 = __builtin_amdgcn_cvt_pk_f32_fp8(eB[k].y, false);
    const f2v d3 = __builtin_amdgcn_cvt_pk_f32_fp8(eB[k].y, true);
    accB[0] += __builtin_elementwise_max(__builtin_elementwise_fma(d0, inv2[0], ttB[0]), zero);
    accB[1] += __builtin_elementwise_max(__builtin_elementwise_fma(d1, inv2[1], ttB[1]), zero);
    accB[2] += __builtin_elementwise_max(__builtin_elementwise_fma(d2, inv2[2], ttB[2]), zero);
    accB[3] += __builtin_elementwise_max(__builtin_elementwise_fma(d3, inv2[3], ttB[3]), zero);
  }
#pragma unroll
  for (int i = 0; i < 4; ++i) {
    const int r0 = 64 + ch + 2 * i;
    obuf[r0 * 65 + colA] = accA[i].x * 0.0625f;
    obuf[(r0 + 1) * 65 + colA] = accA[i].y * 0.0625f;
    obuf[r0 * 65 + colB] = accB[i].x * 0.0625f;
    obuf[(r0 + 1) * 65 + colB] = accB[i].y * 0.0625f;
  }
  __syncthreads();
  // write 128 ch x 64 n, coalesced float4, NT (wave-contiguous, touch-once)
#pragma unroll
  for (int r = 0; r < 8; ++r) {
    const int c = r * 16 + (t >> 4);
    const int n4 = (t & 15) * 4;
    const f4v v = {obuf[c * 65 + n4], obuf[c * 65 + n4 + 1],
                   obuf[c * 65 + n4 + 2], obuf[c * 65 + n4 + 3]};
    __builtin_nontemporal_store(
        v, reinterpret_cast<f4v*>(out + ((size_t)b * 128 + c) * NPTS + n_blk + n4));
  }
}

extern "C" void kernel_launch(void* const* d_in, const int* in_sizes, int n_in,
                              void* d_out, int out_size, void* d_ws, size_t ws_size,
                              hipStream_t stream) {
  const float* feat  = (const float*)d_in[0];
  const int*   knn   = (const int*)d_in[1];
  const float* W1    = (const float*)d_in[2];
  const float* W2    = (const float*)d_in[3];
  const float* gamma = (const float*)d_in[4];
  const float* beta  = (const float*)d_in[5];
  const float* mean  = (const float*)d_in[6];
  const float* var   = (const float*)d_in[7];
  float* out = (float*)d_out;

  u16* lt = (u16*)d_ws;                           // (B,N,64) fp16 local, 16.8 MB
  u8* et = (u8*)(lt + (size_t)NB * NPTS * COUT);  // (B,N,64) fp8 edge, 8.4 MB

  k1_gemm<<<dim3(NB * NPTS / 64), 256, 0, stream>>>(feat, W1, W2, lt, et);
  k2_gather<<<dim3(NB * NPTS / 64), 256, 0, stream>>>(lt, et, knn, gamma, beta,
                                                      mean, var, out);
}